// Round 7
// baseline (305.845 us; speedup 1.0000x reference)
//
#include <hip/hip_runtime.h>
#include <hip/hip_fp16.h>

#define NEG_SLOPE 0.2f
#define NEG_BIG   -1e30f

typedef _Float16 f16x8 __attribute__((ext_vector_type(8)));
typedef _Float16 h2    __attribute__((ext_vector_type(2)));
typedef float    f32x4 __attribute__((ext_vector_type(4)));
union H8 { f16x8 h8; float4 f4; };
union H2x4 { float4 f4; h2 v[4]; _Float16 h[8]; };

static __device__ __forceinline__ h2 habs2(h2 x) {
    union { h2 v; unsigned u; } q; q.v = x; q.u &= 0x7FFF7FFFu; return q.v;
}

#if defined(__has_builtin)
#if __has_builtin(__builtin_amdgcn_fdot2)
#define FDOT2(a, b, c) __builtin_amdgcn_fdot2((a), (b), (c), false)
#endif
#endif
#ifndef FDOT2
#define FDOT2(a, b, c) fmaf((float)(a)[0], (float)(b)[0], \
                       fmaf((float)(a)[1], (float)(b)[1], (c)))
#endif

// ---------------------------------------------------------------- CSR build

__global__ void count_k(const int* __restrict__ dst, int* __restrict__ cnt, int e) {
    int g = blockIdx.x * blockDim.x + threadIdx.x;
    if (g < e) atomicAdd(&cnt[dst[g]], 1);
}

__global__ void scan1(const int* __restrict__ cnt, int* __restrict__ offs,
                      int* __restrict__ partial, int n) {
    __shared__ int s[256];
    int tid = threadIdx.x;
    int g = blockIdx.x * 256 + tid;
    int v = (g < n) ? ((cnt[g] + 3) & ~3) : 0;   // pad each segment to x4
    s[tid] = v;
    __syncthreads();
    for (int off = 1; off < 256; off <<= 1) {
        int t = (tid >= off) ? s[tid - off] : 0;
        __syncthreads();
        s[tid] += t;
        __syncthreads();
    }
    if (g < n) offs[g] = s[tid] - v;            // exclusive within block
    if (tid == 255) partial[blockIdx.x] = s[255];
}

__global__ void scan2(int* __restrict__ partial, int p) {
    __shared__ int s[256];
    int tid = threadIdx.x;
    int v = (tid < p) ? partial[tid] : 0;
    s[tid] = v;
    __syncthreads();
    for (int off = 1; off < 256; off <<= 1) {
        int t = (tid >= off) ? s[tid - off] : 0;
        __syncthreads();
        s[tid] += t;
        __syncthreads();
    }
    if (tid < p) partial[tid] = s[tid] - v;     // exclusive
}

__global__ void scan3(int* __restrict__ offs, const int* __restrict__ partial, int n) {
    int g = blockIdx.x * 256 + threadIdx.x;
    if (g < n) offs[g] += partial[blockIdx.x];
}

__global__ void scan3b(int* __restrict__ offs, const int* __restrict__ cnt, int n) {
    if (blockIdx.x == 0 && threadIdx.x == 0)
        offs[n] = offs[n - 1] + ((cnt[n - 1] + 3) & ~3);
}

__global__ void scatter_k(const int* __restrict__ src, const int* __restrict__ dst,
                          const int* __restrict__ offs, int* __restrict__ cursor,
                          int* __restrict__ csr_src, int e) {
    int g = blockIdx.x * blockDim.x + threadIdx.x;
    if (g < e) {
        int d = dst[g];
        int pos = atomicAdd(&cursor[d], 1);
        csr_src[offs[d] + pos] = src[g];
    }
}

// ------------------------------------------- weight prep: fp32 [K][N] -> fp16 [N][K]

__global__ void wprep4(const float* W0, const float* W1,
                       const float* W2, const float* W3,
                       __half* T0, __half* T1, __half* T2, __half* T3) {
    const float* W; __half* T;
    switch (blockIdx.y) {
        case 0: W = W0; T = T0; break;
        case 1: W = W1; T = T1; break;
        case 2: W = W2; T = T2; break;
        default: W = W3; T = T3; break;
    }
    int idx = blockIdx.x * 256 + threadIdx.x;    // 16384 per matrix
    int n = idx & 127, k = idx >> 7;
    T[(size_t)n * 128 + k] = __float2half(W[(size_t)k * 128 + n]);
}

// ------------------------------------------- MFMA dual GEMM (fp32 A -> fp16 out)

__global__ __launch_bounds__(256) void gemm_mfma(
    const float* __restrict__ A,
    const __half* __restrict__ WtL, const __half* __restrict__ WtR,
    const float* __restrict__ bl, const float* __restrict__ br,
    __half* __restrict__ outl, __half* __restrict__ outr, int nstrips)
{
    const int wid = (blockIdx.x * blockDim.x + threadIdx.x) >> 6;
    if (wid >= nstrips) return;
    const int lane = threadIdx.x & 63;
    const int mrow = lane & 15;
    const int quad = lane >> 4;
    const int base = wid * 16;

    f16x8 afrag[4];
    const float* arow = &A[(size_t)(base + mrow) * 128 + quad * 8];
#pragma unroll
    for (int kc = 0; kc < 4; ++kc) {
        const float4 f0 = *(const float4*)&arow[kc * 32];
        const float4 f1 = *(const float4*)&arow[kc * 32 + 4];
        f16x8 h;
        h[0] = (_Float16)f0.x; h[1] = (_Float16)f0.y;
        h[2] = (_Float16)f0.z; h[3] = (_Float16)f0.w;
        h[4] = (_Float16)f1.x; h[5] = (_Float16)f1.y;
        h[6] = (_Float16)f1.z; h[7] = (_Float16)f1.w;
        afrag[kc] = h;
    }

    const size_t orow = (size_t)(base + mrow) * 128;

#pragma unroll
    for (int c = 0; c < 8; ++c) {
        const size_t wof = (size_t)(c * 16 + mrow) * 128 + quad * 8;
        {
            H8 w0, w1, w2, w3;
            w0.f4 = *(const float4*)&WtL[wof +  0];
            w1.f4 = *(const float4*)&WtL[wof + 32];
            w2.f4 = *(const float4*)&WtL[wof + 64];
            w3.f4 = *(const float4*)&WtL[wof + 96];
            f32x4 acc = {0.f, 0.f, 0.f, 0.f};
            acc = __builtin_amdgcn_mfma_f32_16x16x32_f16(w0.h8, afrag[0], acc, 0, 0, 0);
            acc = __builtin_amdgcn_mfma_f32_16x16x32_f16(w1.h8, afrag[1], acc, 0, 0, 0);
            acc = __builtin_amdgcn_mfma_f32_16x16x32_f16(w2.h8, afrag[2], acc, 0, 0, 0);
            acc = __builtin_amdgcn_mfma_f32_16x16x32_f16(w3.h8, afrag[3], acc, 0, 0, 0);
            const float4 bv = *(const float4*)&bl[c * 16 + quad * 4];
            union { __half2 h2v[2]; float2 f2; } o;
            o.h2v[0] = __floats2half2_rn(acc[0] + bv.x, acc[1] + bv.y);
            o.h2v[1] = __floats2half2_rn(acc[2] + bv.z, acc[3] + bv.w);
            *(float2*)&outl[orow + c * 16 + quad * 4] = o.f2;
        }
        {
            H8 w0, w1, w2, w3;
            w0.f4 = *(const float4*)&WtR[wof +  0];
            w1.f4 = *(const float4*)&WtR[wof + 32];
            w2.f4 = *(const float4*)&WtR[wof + 64];
            w3.f4 = *(const float4*)&WtR[wof + 96];
            f32x4 acc = {0.f, 0.f, 0.f, 0.f};
            acc = __builtin_amdgcn_mfma_f32_16x16x32_f16(w0.h8, afrag[0], acc, 0, 0, 0);
            acc = __builtin_amdgcn_mfma_f32_16x16x32_f16(w1.h8, afrag[1], acc, 0, 0, 0);
            acc = __builtin_amdgcn_mfma_f32_16x16x32_f16(w2.h8, afrag[2], acc, 0, 0, 0);
            acc = __builtin_amdgcn_mfma_f32_16x16x32_f16(w3.h8, afrag[3], acc, 0, 0, 0);
            const float4 bv = *(const float4*)&br[c * 16 + quad * 4];
            union { __half2 h2v[2]; float2 f2; } o;
            o.h2v[0] = __floats2half2_rn(acc[0] + bv.x, acc[1] + bv.y);
            o.h2v[1] = __floats2half2_rn(acc[2] + bv.z, acc[3] + bv.w);
            *(float2*)&outr[orow + c * 16 + quad * 4] = o.f2;
        }
    }
}

// -------------------------------------- per-node online-softmax aggregation
// Persistent waves (grid-stride over nodes). 16 lanes per edge, 4 edge-groups.
// CSR padded to x4 with src=-1 sentinels (no tail divergence).

template <int C>
static __device__ __forceinline__ void attn_step(
    const __half* __restrict__ xl, int idx, int e, int g, int t,
    const h2 ah[4], const h2 xrh[4], const h2 c06, const h2 c04,
    float& m, float& l, float acc[8])
{
    int s[C];
#pragma unroll
    for (int c = 0; c < C; ++c) s[c] = __shfl(idx, e + 4 * c + g);
    H2x4 r[C];
#pragma unroll
    for (int c = 0; c < C; ++c)
        r[c].f4 = *(const float4*)&xl[(size_t)(s[c] < 0 ? 0 : s[c]) * 128 + t * 8];

    float p[C];
#pragma unroll
    for (int c = 0; c < C; ++c) {
        float pp = 0.f;
#pragma unroll
        for (int j = 0; j < 4; ++j) {
            h2 z = r[c].v[j] + xrh[j];           // v_pk_add_f16
            h2 u = z * c06 + habs2(z) * c04;     // leaky_relu(z, 0.2)
            pp = FDOT2(u, ah[j], pp);            // v_dot2_f32_f16
        }
        p[c] = pp;
    }
#pragma unroll
    for (int off = 1; off <= 8; off <<= 1)
#pragma unroll
        for (int c = 0; c < C; ++c) p[c] += __shfl_xor(p[c], off, 64);
#pragma unroll
    for (int c = 0; c < C; ++c) if (s[c] < 0) p[c] = NEG_BIG;

    float mn = m;
#pragma unroll
    for (int c = 0; c < C; ++c) mn = fmaxf(mn, p[c]);
    const float sc = __expf(m - mn);
    float w[C], suml = 0.f;
#pragma unroll
    for (int c = 0; c < C; ++c) { w[c] = __expf(p[c] - mn); suml += w[c]; }
    l = fmaf(l, sc, suml);
#pragma unroll
    for (int k = 0; k < 8; ++k) {
        float tt = 0.f;
#pragma unroll
        for (int c = 0; c < C; ++c)
            tt = fmaf(w[c], (float)r[c].h[k], tt);   // v_fma_mix
        acc[k] = fmaf(acc[k], sc, tt);
    }
    m = mn;
}

__global__ __launch_bounds__(256) void attn_k(
    const __half* __restrict__ xl, const __half* __restrict__ xr,
    const int* __restrict__ offs, const int* __restrict__ csr_src,
    const float* __restrict__ att, const float* __restrict__ bias,
    float* __restrict__ out, int n, int nwaves)
{
    const int wave0 = (blockIdx.x * blockDim.x + threadIdx.x) >> 6;
    const int lane = threadIdx.x & 63;
    const int g = lane >> 4;          // edge group 0..3
    const int t = lane & 15;          // dim slot: dims t*8 .. t*8+7

    // wave-lifetime constants
    h2 ah[4];
    {
        float4 a0 = *(const float4*)&att[t * 8];
        float4 a1 = *(const float4*)&att[t * 8 + 4];
        ah[0] = h2{(_Float16)a0.x, (_Float16)a0.y};
        ah[1] = h2{(_Float16)a0.z, (_Float16)a0.w};
        ah[2] = h2{(_Float16)a1.x, (_Float16)a1.y};
        ah[3] = h2{(_Float16)a1.z, (_Float16)a1.w};
    }
    const h2 c06 = h2{(_Float16)0.6f, (_Float16)0.6f};
    const h2 c04 = h2{(_Float16)0.4f, (_Float16)0.4f};
    const float4 b0 = *(const float4*)&bias[t * 8];
    const float4 b1 = *(const float4*)&bias[t * 8 + 4];

    for (int wid = wave0; wid < n; wid += nwaves) {
        const int i0  = offs[wid];
        const int deg = offs[wid + 1] - i0;   // padded to x4
        H2x4 xrr; xrr.f4 = *(const float4*)&xr[(size_t)wid * 128 + t * 8];

        float m = NEG_BIG, l = 0.f, acc[8];
#pragma unroll
        for (int k = 0; k < 8; ++k) acc[k] = 0.f;

        for (int b = 0; b < deg; b += 64) {
            const int nb = min(64, deg - b);        // multiple of 4
            const int idx = (b + lane < deg) ? csr_src[i0 + b + lane] : -1;

            int e = 0;
            for (; e + 16 <= nb; e += 16)
                attn_step<4>(xl, idx, e, g, t, ah, xrr.v, c06, c04, m, l, acc);
            if (e + 8 <= nb) {
                attn_step<2>(xl, idx, e, g, t, ah, xrr.v, c06, c04, m, l, acc);
                e += 8;
            }
            if (e + 4 <= nb)
                attn_step<1>(xl, idx, e, g, t, ah, xrr.v, c06, c04, m, l, acc);
        }

        // merge the 4 group states (butterfly over offsets 16, 32)
#pragma unroll
        for (int off = 16; off <= 32; off <<= 1) {
            const float mo = __shfl_xor(m, off, 64);
            const float lo = __shfl_xor(l, off, 64);
            float ao[8];
#pragma unroll
            for (int k = 0; k < 8; ++k) ao[k] = __shfl_xor(acc[k], off, 64);
            const float mn = fmaxf(m, mo);
            const float sa = __expf(m - mn);
            const float sb = __expf(mo - mn);
            l = l * sa + lo * sb;
#pragma unroll
            for (int k = 0; k < 8; ++k) acc[k] = acc[k] * sa + ao[k] * sb;
            m = mn;
        }

        if (g == 0) {
            const float inv = 1.0f / fmaxf(l, 1e-16f);
            const float bb[8] = {b0.x, b0.y, b0.z, b0.w, b1.x, b1.y, b1.z, b1.w};
            float o[8];
#pragma unroll
            for (int k = 0; k < 8; ++k)
                o[k] = fmaxf(fmaf(acc[k], inv, bb[k]), 0.f);
            float* orow = &out[(size_t)wid * 128 + t * 8];
            *(float4*)&orow[0] = make_float4(o[0], o[1], o[2], o[3]);
            *(float4*)&orow[4] = make_float4(o[4], o[5], o[6], o[7]);
        }
    }
}

// ---------------------------------------------------------------- launcher

extern "C" void kernel_launch(void* const* d_in, const int* in_sizes, int n_in,
                              void* d_out, int out_size, void* d_ws, size_t ws_size,
                              hipStream_t stream) {
    const float* x    = (const float*)d_in[0];
    const int*   ei   = (const int*)d_in[1];
    const float* Wl1  = (const float*)d_in[2];
    const float* bl1  = (const float*)d_in[3];
    const float* Wr1  = (const float*)d_in[4];
    const float* br1  = (const float*)d_in[5];
    const float* att1 = (const float*)d_in[6];
    const float* b1   = (const float*)d_in[7];
    const float* Wl2  = (const float*)d_in[8];
    const float* bl2  = (const float*)d_in[9];
    const float* Wr2  = (const float*)d_in[10];
    const float* br2  = (const float*)d_in[11];
    const float* att2 = (const float*)d_in[12];
    const float* b2   = (const float*)d_in[13];

    const int N = in_sizes[0] / 128;   // 40000
    const int E = in_sizes[1] / 2;     // 640000
    const int* srcp = ei;
    const int* dstp = ei + E;
    const size_t csrCap = (size_t)E + 4 * (size_t)N;   // padded capacity

    char* ws = (char*)d_ws;
    __half* xl     = (__half*)ws; ws += (size_t)N * 128 * 2;
    __half* xr     = (__half*)ws; ws += (size_t)N * 128 * 2;
    int*   csr_src = (int*)ws;    ws += csrCap * 4;
    int*   offs    = (int*)ws;    ws += ((size_t)N + 4) * 4;
    int*   cnt     = (int*)ws;    ws += (size_t)N * 4;
    int*   cursor  = (int*)ws;    ws += (size_t)N * 4;
    int*   partial = (int*)ws;    ws += 1024;
    __half* Wt1l   = (__half*)ws; ws += 128 * 128 * 2;
    __half* Wt1r   = (__half*)ws; ws += 128 * 128 * 2;
    __half* Wt2l   = (__half*)ws; ws += 128 * 128 * 2;
    __half* Wt2r   = (__half*)ws; ws += 128 * 128 * 2;
    float* h = (float*)d_out;          // layer-1 activations (rewritten by layer 2)

    const int scanBlocks = (N + 255) / 256;       // 157
    const int eBlocks = (E + 255) / 256;          // 2500

    hipMemsetAsync(cnt, 0, (size_t)N * 2 * 4, stream);       // cnt + cursor
    hipMemsetAsync(csr_src, 0xFF, csrCap * 4, stream);       // pad sentinel -1

    // ---- weight prep (one launch) ----
    wprep4<<<dim3(64, 4), 256, 0, stream>>>(Wl1, Wr1, Wl2, Wr2,
                                            Wt1l, Wt1r, Wt2l, Wt2r);

    // ---- CSR by dst, segments padded to x4 (shared by both layers) ----
    count_k<<<eBlocks, 256, 0, stream>>>(dstp, cnt, E);
    scan1<<<scanBlocks, 256, 0, stream>>>(cnt, offs, partial, N);
    scan2<<<1, 256, 0, stream>>>(partial, scanBlocks);
    scan3<<<scanBlocks, 256, 0, stream>>>(offs, partial, N);
    scan3b<<<1, 64, 0, stream>>>(offs, cnt, N);
    scatter_k<<<eBlocks, 256, 0, stream>>>(srcp, dstp, offs, cursor, csr_src, E);

    const int nstrips = N / 16;                   // 2500
    const int gemmBlocks = (nstrips + 3) / 4;     // 625 (4 waves/block)
    const int attnBlocks = 2048;                  // persistent: 8 blocks/CU
    const int nwaves = attnBlocks * 4;            // 8192 waves

    // ---- layer 1 ----
    gemm_mfma<<<gemmBlocks, 256, 0, stream>>>(x, Wt1l, Wt1r, bl1, br1, xl, xr, nstrips);
    attn_k<<<attnBlocks, 256, 0, stream>>>(xl, xr, offs, csr_src, att1, b1, h, N, nwaves);

    // ---- layer 2 ----
    gemm_mfma<<<gemmBlocks, 256, 0, stream>>>(h, Wt2l, Wt2r, bl2, br2, xl, xr, nstrips);
    attn_k<<<attnBlocks, 256, 0, stream>>>(xl, xr, offs, csr_src, att2, b2,
                                           (float*)d_out, N, nwaves);
}